// Round 4
// baseline (59.561 us; speedup 1.0000x reference)
//
#include <hip/hip_runtime.h>

// Problem constants (from setup_inputs): B=256 batches, N=512 keypoints.
#define BATCH 256
#define NPTS  512
#define TPB   256            // 2 points per thread
#define PPT   (NPTS / TPB)
#define CENTER_X 0.5f
// Flag value signalling "partial published". Must differ from the harness's
// 0xAA poison pattern (0xAAAAAAAA), which d_ws is reset to before EVERY launch.
#define MAGIC 0x3C96A5F1

// Single kernel, BATCH+1 blocks.
// Blocks 0..BATCH-1: per-batch closed-form reduction. Per symmetric class
// k in {0,1,2} with u = x - cx:
//   sum_{i<j} (x_i+x_j-2cx)^2 = (m-2)*su2 + su^2
//   sum_{i<j} (y_i-y_j)^2     = m*sy2 - sy^2
//   pairs                     = m*(m-1)/2
// Each publishes (total, count) then release-stores flags[b]=MAGIC.
// Block BATCH: each thread acquire-spins on its own flag word (no shared
// ticket -> no RMW serialization), then reduces all 256 partials in a fixed
// order (deterministic) and writes total/max(count,1).
__global__ __launch_bounds__(TPB) void sym_onepass(
    const float* __restrict__ kp,   // [B, N, 2]
    const int* __restrict__ cls,    // [B, N]
    float* __restrict__ out,
    int* __restrict__ flags,        // [BATCH]
    float* __restrict__ totals,     // [BATCH]
    float* __restrict__ counts) {   // [BATCH]
  const int b = blockIdx.x;
  const int t = threadIdx.x;
  const int wave = t >> 6;
  const int lane = t & 63;

  if (b < BATCH) {
    // ---- worker block: per-batch partial ----
    float v[15];
#pragma unroll
    for (int i = 0; i < 15; ++i) v[i] = 0.0f;

#pragma unroll
    for (int p = 0; p < PPT; ++p) {
      const int idx = b * NPTS + p * TPB + t;
      const float2 q = ((const float2*)kp)[idx];
      const int c = cls[idx];
      const float u = q.x - CENTER_X;
      const float y = q.y;
#pragma unroll
      for (int k = 0; k < 3; ++k) {
        const float sel = (c == k) ? 1.0f : 0.0f;
        v[5 * k + 0] += sel * u;
        v[5 * k + 1] += sel * u * u;
        v[5 * k + 2] += sel * y;
        v[5 * k + 3] += sel * y * y;
        v[5 * k + 4] += sel;
      }
    }

    // 64-lane butterfly reduce all 15 values
#pragma unroll
    for (int off = 32; off >= 1; off >>= 1) {
#pragma unroll
      for (int i = 0; i < 15; ++i) v[i] += __shfl_down(v[i], off, 64);
    }

    __shared__ float lds[TPB / 64][15];
    if (lane == 0) {
#pragma unroll
      for (int i = 0; i < 15; ++i) lds[wave][i] = v[i];
    }
    __syncthreads();

    if (t == 0) {
      float total = 0.0f, count = 0.0f;
#pragma unroll
      for (int k = 0; k < 3; ++k) {
        float su = 0.f, su2 = 0.f, sy = 0.f, sy2 = 0.f, m = 0.f;
#pragma unroll
        for (int w = 0; w < TPB / 64; ++w) {
          su  += lds[w][5 * k + 0];
          su2 += lds[w][5 * k + 1];
          sy  += lds[w][5 * k + 2];
          sy2 += lds[w][5 * k + 3];
          m   += lds[w][5 * k + 4];
        }
        total += (m - 2.0f) * su2 + su * su + m * sy2 - sy * sy;
        count += 0.5f * m * (m - 1.0f);
      }
      __hip_atomic_store(&totals[b], total, __ATOMIC_RELAXED, __HIP_MEMORY_SCOPE_AGENT);
      __hip_atomic_store(&counts[b], count, __ATOMIC_RELAXED, __HIP_MEMORY_SCOPE_AGENT);
      // release: orders the partial stores before the flag
      __hip_atomic_store(&flags[b], MAGIC, __ATOMIC_RELEASE, __HIP_MEMORY_SCOPE_AGENT);
    }
  } else {
    // ---- consumer block: wait for all partials, reduce, write mean ----
    while (__hip_atomic_load(&flags[t], __ATOMIC_ACQUIRE,
                             __HIP_MEMORY_SCOPE_AGENT) != MAGIC) {
      __builtin_amdgcn_s_sleep(2);
    }
    float T = __hip_atomic_load(&totals[t], __ATOMIC_RELAXED, __HIP_MEMORY_SCOPE_AGENT);
    float C = __hip_atomic_load(&counts[t], __ATOMIC_RELAXED, __HIP_MEMORY_SCOPE_AGENT);

#pragma unroll
    for (int off = 32; off >= 1; off >>= 1) {
      T += __shfl_down(T, off, 64);
      C += __shfl_down(C, off, 64);
    }
    __shared__ float lt[TPB / 64], lc[TPB / 64];
    if (lane == 0) { lt[wave] = T; lc[wave] = C; }
    __syncthreads();
    if (t == 0) {
      float Ts = 0.f, Cs = 0.f;
#pragma unroll
      for (int w = 0; w < TPB / 64; ++w) { Ts += lt[w]; Cs += lc[w]; }
      out[0] = Ts / fmaxf(Cs, 1.0f);
    }
  }
}

extern "C" void kernel_launch(void* const* d_in, const int* in_sizes, int n_in,
                              void* d_out, int out_size, void* d_ws, size_t ws_size,
                              hipStream_t stream) {
  const float* kp = (const float*)d_in[0];   // [B, N, 2] float32
  const int* cls = (const int*)d_in[1];      // [B, N] int32
  float* out = (float*)d_out;

  int* flags = (int*)d_ws;                   // [256] ints   @ 0
  float* totals = (float*)d_ws + 512;        // [256] floats @ 2 KiB
  float* counts = totals + BATCH;            // [256] floats @ 3 KiB

  sym_onepass<<<BATCH + 1, TPB, 0, stream>>>(kp, cls, out, flags, totals, counts);
}

// Round 5
// 57.739 us; speedup vs baseline: 1.0316x; 1.0316x over previous
//
#include <hip/hip_runtime.h>

// Problem constants (from setup_inputs): B=256 batches, N=512 keypoints.
#define BATCH 256
#define NPTS  512
#define TPB   256            // 2 points per thread
#define PPT   (NPTS / TPB)
#define CENTER_X 0.5f

// Kernel 1: one block per batch, 256 threads, 2 points/thread.
// Per symmetric class k in {0,1,2} with u = x - cx:
//   sum_{i<j} (x_i+x_j-2cx)^2 = (m-2)*su2 + su^2
//   sum_{i<j} (y_i-y_j)^2     = m*sy2 - sy^2
//   pairs                     = m*(m-1)/2
// Publishes per-batch (total, count) as one interleaved float2 at ws2[b].
__global__ __launch_bounds__(TPB) void sym_batch_reduce(
    const float* __restrict__ kp,   // [B, N, 2]
    const int* __restrict__ cls,    // [B, N]
    float2* __restrict__ ws2) {     // [BATCH] (total, count)
  const int b = blockIdx.x;
  const int t = threadIdx.x;
  const int wave = t >> 6;
  const int lane = t & 63;

  float v[15];
#pragma unroll
  for (int i = 0; i < 15; ++i) v[i] = 0.0f;

#pragma unroll
  for (int p = 0; p < PPT; ++p) {
    const int idx = b * NPTS + p * TPB + t;
    const float2 q = ((const float2*)kp)[idx];
    const int c = cls[idx];
    const float u = q.x - CENTER_X;
    const float y = q.y;
#pragma unroll
    for (int k = 0; k < 3; ++k) {
      const float sel = (c == k) ? 1.0f : 0.0f;
      v[5 * k + 0] += sel * u;
      v[5 * k + 1] += sel * u * u;
      v[5 * k + 2] += sel * y;
      v[5 * k + 3] += sel * y * y;
      v[5 * k + 4] += sel;
    }
  }

  // 64-lane butterfly reduce all 15 values
#pragma unroll
  for (int off = 32; off >= 1; off >>= 1) {
#pragma unroll
    for (int i = 0; i < 15; ++i) v[i] += __shfl_down(v[i], off, 64);
  }

  __shared__ float lds[TPB / 64][15];
  if (lane == 0) {
#pragma unroll
    for (int i = 0; i < 15; ++i) lds[wave][i] = v[i];
  }
  __syncthreads();

  if (t == 0) {
    float total = 0.0f, count = 0.0f;
#pragma unroll
    for (int k = 0; k < 3; ++k) {
      float su = 0.f, su2 = 0.f, sy = 0.f, sy2 = 0.f, m = 0.f;
#pragma unroll
      for (int w = 0; w < TPB / 64; ++w) {
        su  += lds[w][5 * k + 0];
        su2 += lds[w][5 * k + 1];
        sy  += lds[w][5 * k + 2];
        sy2 += lds[w][5 * k + 3];
        m   += lds[w][5 * k + 4];
      }
      total += (m - 2.0f) * su2 + su * su + m * sy2 - sy * sy;
      count += 0.5f * m * (m - 1.0f);
    }
    ws2[b] = make_float2(total, count);
  }
}

// Kernel 2: single wave (64 threads). Each thread reduces 4 batches via
// coalesced float2 loads; butterfly over 64 lanes; lane 0 writes the mean.
// No LDS, no __syncthreads -> shortest critical path on the dependent node.
__global__ __launch_bounds__(64) void sym_final_reduce(
    const float2* __restrict__ ws2, float* __restrict__ out) {
  const int t = threadIdx.x;
  float T = 0.f, C = 0.f;
#pragma unroll
  for (int r = 0; r < BATCH / 64; ++r) {
    const float2 p = ws2[r * 64 + t];
    T += p.x;
    C += p.y;
  }
#pragma unroll
  for (int off = 32; off >= 1; off >>= 1) {
    T += __shfl_down(T, off, 64);
    C += __shfl_down(C, off, 64);
  }
  if (t == 0) out[0] = T / fmaxf(C, 1.0f);
}

extern "C" void kernel_launch(void* const* d_in, const int* in_sizes, int n_in,
                              void* d_out, int out_size, void* d_ws, size_t ws_size,
                              hipStream_t stream) {
  const float* kp = (const float*)d_in[0];   // [B, N, 2] float32
  const int* cls = (const int*)d_in[1];      // [B, N] int32
  float* out = (float*)d_out;
  float2* ws2 = (float2*)d_ws;               // needs BATCH float2 = 2 KiB

  sym_batch_reduce<<<BATCH, TPB, 0, stream>>>(kp, cls, ws2);
  sym_final_reduce<<<1, 64, 0, stream>>>(ws2, out);
}